// Round 3
// baseline (1235.453 us; speedup 1.0000x reference)
//
#include <hip/hip_runtime.h>

#define D_DIM 128
#define N_ENT 100000
#define R_REL 8
#define E_EDGE 131072
#define B_HEAD 32768
#define NH_PAD 100352  // 1024*98 >= N_ENT

// ---------- CSR build ----------
__global__ __launch_bounds__(256) void zero_counts(int* __restrict__ p) {
  p[blockIdx.x * 256 + threadIdx.x] = 0;  // exact grid
}

__global__ __launch_bounds__(256) void hist_edges(const int* __restrict__ erow,
                                                  int* __restrict__ cnt) {
  int r = blockIdx.y;
  int e = blockIdx.x * 256 + threadIdx.x;
  int row = erow[(size_t)r * E_EDGE + e];
  atomicAdd(cnt + r * B_HEAD + row, 1);
}

__global__ __launch_bounds__(256) void hist_heads(const int* __restrict__ head,
                                                  int* __restrict__ cnt) {
  int i = blockIdx.x * 256 + threadIdx.x;  // < R*B
  atomicAdd(cnt + head[i], 1);
}

// exclusive scan of cnt[r*B..] -> cur[r*B..] with base r*E (one block per relation)
__global__ __launch_bounds__(1024) void scan_rel(const int* __restrict__ cnt,
                                                 int* __restrict__ cur) {
  int r = blockIdx.x, t = threadIdx.x;
  const int* c = cnt + (size_t)r * B_HEAD;
  int* q = cur + (size_t)r * B_HEAD;
  int base = t * 32;
  int s = 0;
#pragma unroll
  for (int k = 0; k < 32; ++k) s += c[base + k];
  __shared__ int ps[1024];
  ps[t] = s;
  __syncthreads();
  for (int off = 1; off < 1024; off <<= 1) {
    int v = (t >= off) ? ps[t - off] : 0;
    __syncthreads();
    ps[t] += v;
    __syncthreads();
  }
  int g = r * E_EDGE + ps[t] - s;
  for (int k = 0; k < 32; ++k) {
    q[base + k] = g;
    g += c[base + k];
  }
}

__global__ __launch_bounds__(1024) void scan_heads(const int* __restrict__ cnt,
                                                   int* __restrict__ cur) {
  int t = threadIdx.x;
  int base = t * 98;
  int s = 0;
  for (int k = 0; k < 98; ++k) {
    int i = base + k;
    if (i < N_ENT) s += cnt[i];
  }
  __shared__ int ps[1024];
  ps[t] = s;
  __syncthreads();
  for (int off = 1; off < 1024; off <<= 1) {
    int v = (t >= off) ? ps[t - off] : 0;
    __syncthreads();
    ps[t] += v;
    __syncthreads();
  }
  int g = ps[t] - s;
  for (int k = 0; k < 98; ++k) {
    int i = base + k;
    if (i < N_ENT) {
      cur[i] = g;
      g += cnt[i];
    }
  }
}

__global__ __launch_bounds__(256) void scatter_edges(const int* __restrict__ erow,
                                                     const int* __restrict__ ecol,
                                                     const float* __restrict__ ew,
                                                     int* __restrict__ cur,
                                                     int2* __restrict__ sColW) {
  int r = blockIdx.y;
  int e = blockIdx.x * 256 + threadIdx.x;
  size_t idx = (size_t)r * E_EDGE + e;
  int row = erow[idx];
  int pos = atomicAdd(cur + r * B_HEAD + row, 1);
  sColW[pos] = make_int2(ecol[idx], __float_as_int(ew[idx]));
}

__global__ __launch_bounds__(256) void scatter_heads(const int* __restrict__ head,
                                                     int* __restrict__ cur,
                                                     int* __restrict__ list) {
  int i = blockIdx.x * 256 + threadIdx.x;  // flat (r,row) id
  int pos = atomicAdd(cur + head[i], 1);
  list[pos] = i;
}

// ---------- aggregation: one wave per (r,row); agg[row_local][:] = sum w*tail[col][:]
__global__ __launch_bounds__(256) void csr_agg(const float* __restrict__ tail,
                                               const int* __restrict__ end_e,
                                               const int* __restrict__ cnt_e,
                                               const int2* __restrict__ sColW,
                                               float* __restrict__ agg, int r0) {
  int wid = (blockIdx.x << 2) + (threadIdx.x >> 6);  // chunk-local row id
  int lane = threadIdx.x & 63;
  int f = r0 * B_HEAD + wid;  // global (r,row) id
  int cn = cnt_e[f];
  int s = end_e[f] - cn;
  const float2* tail2 = (const float2*)tail;
  float2 a0 = {0.f, 0.f}, a1 = {0.f, 0.f};
  int k = 0;
  for (; k + 2 <= cn; k += 2) {
    int2 e0 = sColW[s + k];
    int2 e1 = sColW[s + k + 1];
    float2 t0 = tail2[(size_t)e0.x * 64 + lane];
    float2 t1 = tail2[(size_t)e1.x * 64 + lane];
    float w0 = __int_as_float(e0.y), w1 = __int_as_float(e1.y);
    a0.x += w0 * t0.x; a0.y += w0 * t0.y;
    a1.x += w1 * t1.x; a1.y += w1 * t1.y;
  }
  if (k < cn) {
    int2 e0 = sColW[s + k];
    float2 t0 = tail2[(size_t)e0.x * 64 + lane];
    float w0 = __int_as_float(e0.y);
    a0.x += w0 * t0.x; a0.y += w0 * t0.y;
  }
  a0.x += a1.x; a0.y += a1.y;
  ((float2*)agg)[(size_t)wid * 64 + lane] = a0;
}

// ---------- GEMMs ----------
// Transpose rel_W [r][i][o] -> relT [r][o][i]
__global__ __launch_bounds__(256) void transpose_relW(const float* __restrict__ relW,
                                                      float* __restrict__ relT) {
  __shared__ float t[32][33];
  int r = blockIdx.y;
  int i0 = (blockIdx.x >> 2) * 32;
  int o0 = (blockIdx.x & 3) * 32;
  int tx = threadIdx.x & 31, ty = threadIdx.x >> 5;
  const float* src = relW + (size_t)r * D_DIM * D_DIM;
  float* dst = relT + (size_t)r * D_DIM * D_DIM;
#pragma unroll
  for (int k = 0; k < 32; k += 8) t[ty + k][tx] = src[(i0 + ty + k) * D_DIM + o0 + tx];
  __syncthreads();
#pragma unroll
  for (int k = 0; k < 32; k += 8) dst[(o0 + ty + k) * D_DIM + i0 + tx] = t[tx][ty + k];
}

// out[n][o] = sum_i A[n][i]*Wm[o][i]; 32-row tile, thread tile 4x4, XOR-swizzled W in LDS.
// REL=true: per-relation A/out (in-place safe: all A rows staged before any write).
template <bool REL>
__global__ __launch_bounds__(256) void gemm_k(const float* __restrict__ Abase,
                                              const float* __restrict__ Wbase,
                                              float* __restrict__ Obase, int r0) {
  __shared__ float wsw[64 * D_DIM];
  __shared__ float As[32 * 132];
  int tid = threadIdx.x;
  const float* A;
  const float* Wm;
  float* Out;
  if (REL) {
    A = Abase + (size_t)blockIdx.y * B_HEAD * D_DIM;
    Wm = Wbase + (size_t)(r0 + blockIdx.y) * D_DIM * D_DIM;
    Out = Obase + (size_t)blockIdx.y * B_HEAD * D_DIM;
  } else {
    A = Abase;
    Wm = Wbase;
    Out = Obase;
  }
  int rowbase = blockIdx.x * 32;
  float4* wsw4 = (float4*)wsw;
  float4* As4 = (float4*)As;
  int lane_o = tid & 31;
  int row0 = (tid >> 5) << 2;
  float acc[4][4] = {};
  {
    const float4* A4 = (const float4*)A;
#pragma unroll
    for (int j = 0; j < 4; ++j) {
      int e4 = tid + j * 256;
      int n = e4 >> 5, i4 = e4 & 31;
      As4[n * 33 + i4] = A4[((size_t)(rowbase + n) << 5) + i4];
    }
  }
  for (int h = 0; h < 2; ++h) {
    const float4* W4 = (const float4*)(Wm + (size_t)(64 * h) * D_DIM);
#pragma unroll
    for (int j = 0; j < 8; ++j) {
      int e4 = tid + j * 256;
      int o = e4 >> 5, i4 = e4 & 31;
      wsw4[(o << 5) + ((i4 ^ o) & 31)] = W4[e4];
    }
    __syncthreads();
#pragma unroll
    for (int i4 = 0; i4 < 32; ++i4) {
      float4 wv[2], av[4];
#pragma unroll
      for (int c = 0; c < 2; ++c) {
        int o = lane_o + 32 * c;
        wv[c] = wsw4[(o << 5) + ((i4 ^ o) & 31)];
      }
#pragma unroll
      for (int r = 0; r < 4; ++r) av[r] = As4[(row0 + r) * 33 + i4];
#pragma unroll
      for (int r = 0; r < 4; ++r)
#pragma unroll
        for (int c = 0; c < 2; ++c)
          acc[r][2 * h + c] += av[r].x * wv[c].x + av[r].y * wv[c].y +
                               av[r].z * wv[c].z + av[r].w * wv[c].w;
    }
    __syncthreads();
  }
#pragma unroll
  for (int r = 0; r < 4; ++r) {
    float* orow = Out + (size_t)(rowbase + row0 + r) * D_DIM;
#pragma unroll
    for (int j = 0; j < 4; ++j) orow[lane_o + 32 * j] = acc[r][j];
  }
}

// out[n] (+)= sum of upd rows mapped to entity n (within [f0,f1)), optional relu.
__global__ __launch_bounds__(256) void final_add(const int* __restrict__ end_h,
                                                 const int* __restrict__ cnt_h,
                                                 const int* __restrict__ list,
                                                 const float* __restrict__ upd,
                                                 float* __restrict__ out, int f0,
                                                 int f1, int doRelu) {
  int n = blockIdx.x * 8 + (threadIdx.x >> 5);
  int lane = threadIdx.x & 31;
  if (n >= N_ENT) return;
  float4* o4 = (float4*)out + (size_t)n * 32 + lane;
  float4 v = *o4;
  int c = cnt_h[n];
  int s = end_h[n] - c;
  for (int k = 0; k < c; ++k) {
    int f = list[s + k];
    if (f < f0 || f >= f1) continue;
    const float4* u4 = (const float4*)upd + (size_t)(f - f0) * 32 + lane;
    float4 u = *u4;
    v.x += u.x; v.y += u.y; v.z += u.z; v.w += u.w;
  }
  if (doRelu) {
    v.x = fmaxf(v.x, 0.f); v.y = fmaxf(v.y, 0.f);
    v.z = fmaxf(v.z, 0.f); v.w = fmaxf(v.w, 0.f);
  }
  *o4 = v;
}

extern "C" void kernel_launch(void* const* d_in, const int* in_sizes, int n_in,
                              void* d_out, int out_size, void* d_ws, size_t ws_size,
                              hipStream_t stream) {
  const float* x = (const float*)d_in[0];
  const float* tail = (const float*)d_in[1];
  const float* W = (const float*)d_in[2];
  const float* relW = (const float*)d_in[3];
  const float* ew = (const float*)d_in[4];
  const int* erow = (const int*)d_in[5];
  const int* ecol = (const int*)d_in[6];
  const int* head = (const int*)d_in[7];
  float* out = (float*)d_out;

  // ws layout (16B-aligned chunks):
  char* p = (char*)d_ws;
  float* relT = (float*)p;   p += (size_t)R_REL * D_DIM * D_DIM * 4;
  int* cnt_e = (int*)p;      p += (size_t)R_REL * B_HEAD * 4;
  int* cnt_h = (int*)p;      p += (size_t)NH_PAD * 4;
  int* cur_e = (int*)p;      p += (size_t)R_REL * B_HEAD * 4;  // becomes end_e
  int* cur_h = (int*)p;      p += (size_t)NH_PAD * 4;          // becomes end_h
  int* list_h = (int*)p;     p += (size_t)R_REL * B_HEAD * 4;
  int2* sColW = (int2*)p;    p += (size_t)R_REL * E_EDGE * 8;
  float* agg = (float*)p;    // chunk * B * D floats (in-place: agg -> upd)
  size_t fixed = (size_t)(p - (char*)d_ws);
  size_t per_rel = (size_t)B_HEAD * D_DIM * 4;
  size_t avail = (ws_size > fixed) ? ws_size - fixed : 0;
  int chunk = (int)(avail / per_rel);
  if (chunk > R_REL) chunk = R_REL;
  if (chunk < 1) chunk = 1;

  zero_counts<<<dim3((R_REL * B_HEAD + NH_PAD) / 256), 256, 0, stream>>>(cnt_e);
  transpose_relW<<<dim3(16, R_REL), 256, 0, stream>>>(relW, relT);

  hist_edges<<<dim3(E_EDGE / 256, R_REL), 256, 0, stream>>>(erow, cnt_e);
  hist_heads<<<dim3(R_REL * B_HEAD / 256), 256, 0, stream>>>(head, cnt_h);
  scan_rel<<<dim3(R_REL), 1024, 0, stream>>>(cnt_e, cur_e);
  scan_heads<<<dim3(1), 1024, 0, stream>>>(cnt_h, cur_h);
  scatter_edges<<<dim3(E_EDGE / 256, R_REL), 256, 0, stream>>>(erow, ecol, ew, cur_e,
                                                               sColW);
  scatter_heads<<<dim3(R_REL * B_HEAD / 256), 256, 0, stream>>>(head, cur_h, list_h);

  gemm_k<false><<<dim3(N_ENT / 32), 256, 0, stream>>>(x, W, out, 0);

  for (int r0 = 0; r0 < R_REL; r0 += chunk) {
    int c = (R_REL - r0 < chunk) ? (R_REL - r0) : chunk;
    csr_agg<<<dim3(c * B_HEAD / 4), 256, 0, stream>>>(tail, cur_e, cnt_e, sColW, agg,
                                                      r0);
    gemm_k<true><<<dim3(B_HEAD / 32, c), 256, 0, stream>>>(agg, relT, agg, r0);
    final_add<<<dim3((N_ENT + 7) / 8), 256, 0, stream>>>(
        cur_h, cnt_h, list_h, agg, out, r0 * B_HEAD, (r0 + c) * B_HEAD,
        (r0 + c == R_REL) ? 1 : 0);
  }
}

// Round 4
// 787.333 us; speedup vs baseline: 1.5692x; 1.5692x over previous
//
#include <hip/hip_runtime.h>

#define D_DIM 128
#define N_ENT 100000
#define R_REL 8
#define E_EDGE 131072
#define B_HEAD 32768
#define NH_PAD 100352  // 1024*98 >= N_ENT

// ---------- CSR build ----------
__global__ __launch_bounds__(256) void zero_counts(int* __restrict__ p) {
  p[blockIdx.x * 256 + threadIdx.x] = 0;  // exact grid
}

__global__ __launch_bounds__(256) void hist_edges(const int* __restrict__ erow,
                                                  int* __restrict__ cnt) {
  int r = blockIdx.y;
  int e = blockIdx.x * 256 + threadIdx.x;
  int row = erow[(size_t)r * E_EDGE + e];
  atomicAdd(cnt + r * B_HEAD + row, 1);
}

__global__ __launch_bounds__(256) void hist_heads(const int* __restrict__ head,
                                                  int* __restrict__ cnt) {
  int i = blockIdx.x * 256 + threadIdx.x;  // < R*B
  atomicAdd(cnt + head[i], 1);
}

// exclusive scan of cnt[r*B..] -> cur[r*B..] with base r*E (one block per relation)
__global__ __launch_bounds__(1024) void scan_rel(const int* __restrict__ cnt,
                                                 int* __restrict__ cur) {
  int r = blockIdx.x, t = threadIdx.x;
  const int* c = cnt + (size_t)r * B_HEAD;
  int* q = cur + (size_t)r * B_HEAD;
  int base = t * 32;
  int s = 0;
#pragma unroll
  for (int k = 0; k < 32; ++k) s += c[base + k];
  __shared__ int ps[1024];
  ps[t] = s;
  __syncthreads();
  for (int off = 1; off < 1024; off <<= 1) {
    int v = (t >= off) ? ps[t - off] : 0;
    __syncthreads();
    ps[t] += v;
    __syncthreads();
  }
  int g = r * E_EDGE + ps[t] - s;
  for (int k = 0; k < 32; ++k) {
    q[base + k] = g;
    g += c[base + k];
  }
}

__global__ __launch_bounds__(1024) void scan_heads(const int* __restrict__ cnt,
                                                   int* __restrict__ cur) {
  int t = threadIdx.x;
  int base = t * 98;
  int s = 0;
  for (int k = 0; k < 98; ++k) {
    int i = base + k;
    if (i < N_ENT) s += cnt[i];
  }
  __shared__ int ps[1024];
  ps[t] = s;
  __syncthreads();
  for (int off = 1; off < 1024; off <<= 1) {
    int v = (t >= off) ? ps[t - off] : 0;
    __syncthreads();
    ps[t] += v;
    __syncthreads();
  }
  int g = ps[t] - s;
  for (int k = 0; k < 98; ++k) {
    int i = base + k;
    if (i < N_ENT) {
      cur[i] = g;
      g += cnt[i];
    }
  }
}

__global__ __launch_bounds__(256) void scatter_edges(const int* __restrict__ erow,
                                                     const int* __restrict__ ecol,
                                                     const float* __restrict__ ew,
                                                     int* __restrict__ cur,
                                                     int2* __restrict__ sColW) {
  int r = blockIdx.y;
  int e = blockIdx.x * 256 + threadIdx.x;
  size_t idx = (size_t)r * E_EDGE + e;
  int row = erow[idx];
  int pos = atomicAdd(cur + r * B_HEAD + row, 1);
  sColW[pos] = make_int2(ecol[idx], __float_as_int(ew[idx]));
}

__global__ __launch_bounds__(256) void scatter_heads(const int* __restrict__ head,
                                                     int* __restrict__ cur,
                                                     int* __restrict__ list) {
  int i = blockIdx.x * 256 + threadIdx.x;  // flat (r,row) id
  int pos = atomicAdd(cur + head[i], 1);
  list[pos] = i;
}

// ---------- aggregation: one wave per (r,row); agg[row_local][:] = sum w*tail[col][:]
__global__ __launch_bounds__(256) void csr_agg(const float* __restrict__ tail,
                                               const int* __restrict__ end_e,
                                               const int* __restrict__ cnt_e,
                                               const int2* __restrict__ sColW,
                                               float* __restrict__ agg, int r0) {
  int wid = (blockIdx.x << 2) + (threadIdx.x >> 6);  // chunk-local row id
  int lane = threadIdx.x & 63;
  int f = r0 * B_HEAD + wid;  // global (r,row) id
  int cn = cnt_e[f];
  int s = end_e[f] - cn;
  const float2* tail2 = (const float2*)tail;
  float2 a0 = {0.f, 0.f}, a1 = {0.f, 0.f};
  int k = 0;
  for (; k + 2 <= cn; k += 2) {
    int2 e0 = sColW[s + k];
    int2 e1 = sColW[s + k + 1];
    float2 t0 = tail2[(size_t)e0.x * 64 + lane];
    float2 t1 = tail2[(size_t)e1.x * 64 + lane];
    float w0 = __int_as_float(e0.y), w1 = __int_as_float(e1.y);
    a0.x += w0 * t0.x; a0.y += w0 * t0.y;
    a1.x += w1 * t1.x; a1.y += w1 * t1.y;
  }
  if (k < cn) {
    int2 e0 = sColW[s + k];
    float2 t0 = tail2[(size_t)e0.x * 64 + lane];
    float w0 = __int_as_float(e0.y);
    a0.x += w0 * t0.x; a0.y += w0 * t0.y;
  }
  a0.x += a1.x; a0.y += a1.y;
  ((float2*)agg)[(size_t)wid * 64 + lane] = a0;
}

// ---------- GEMMs ----------
// Transpose rel_W [r][i][o] -> relT [r][o][i]
__global__ __launch_bounds__(256) void transpose_relW(const float* __restrict__ relW,
                                                      float* __restrict__ relT) {
  __shared__ float t[32][33];
  int r = blockIdx.y;
  int i0 = (blockIdx.x >> 2) * 32;
  int o0 = (blockIdx.x & 3) * 32;
  int tx = threadIdx.x & 31, ty = threadIdx.x >> 5;
  const float* src = relW + (size_t)r * D_DIM * D_DIM;
  float* dst = relT + (size_t)r * D_DIM * D_DIM;
#pragma unroll
  for (int k = 0; k < 32; k += 8) t[ty + k][tx] = src[(i0 + ty + k) * D_DIM + o0 + tx];
  __syncthreads();
#pragma unroll
  for (int k = 0; k < 32; k += 8) dst[(o0 + ty + k) * D_DIM + i0 + tx] = t[tx][ty + k];
}

// out[n][o] = sum_i A[n][i]*Wm[o][i]; Wm is [o][i].
// 64-row block tile, 256 threads, thread tile 8 rows x 4 cols (cols o = lane_o+32j).
// W-only LDS (two 32KB k-halves, XOR-swizzled); A via global broadcast loads (L1).
// In-place safe (REL): every store depends on the full k-loop of its own rows.
template <bool REL>
__global__ __launch_bounds__(256) void gemm_k(const float* __restrict__ Abase,
                                              const float* __restrict__ Wbase,
                                              float* __restrict__ Obase, int r0,
                                              int nrows) {
  __shared__ float4 w4[128 * 16];  // 32KB: [o][k4'] swizzled
  int tid = threadIdx.x;
  const float* A;
  const float* Wm;
  float* Out;
  if (REL) {
    A = Abase + (size_t)blockIdx.y * B_HEAD * D_DIM;
    Wm = Wbase + (size_t)(r0 + blockIdx.y) * D_DIM * D_DIM;
    Out = Obase + (size_t)blockIdx.y * B_HEAD * D_DIM;
  } else {
    A = Abase;
    Wm = Wbase;
    Out = Obase;
  }
  const float4* A4 = (const float4*)A;
  const float4* W4 = (const float4*)Wm;
  int lane_o = tid & 31;
  int rowg = tid >> 5;  // 0..7
  int row0 = blockIdx.x * 64 + rowg * 8;
  // per-row clamped base offsets (clamp only matters for the <false> tail block)
  size_t rowOff[8];
#pragma unroll
  for (int r = 0; r < 8; ++r) {
    int rr = row0 + r;
    if (rr > nrows - 1) rr = nrows - 1;
    rowOff[r] = (size_t)rr * 32;
  }
  float acc[8][4] = {};
  for (int h = 0; h < 2; ++h) {
    if (h) __syncthreads();
    // stage half of W: 2048 float4 (128 o x 16 k4'), swizzled slot = (k'^o)&15
#pragma unroll
    for (int t = 0; t < 8; ++t) {
      int e = tid + t * 256;
      int o = e >> 4, kk = e & 15;
      w4[o * 16 + ((kk ^ o) & 15)] = W4[o * 32 + h * 16 + kk];
    }
    __syncthreads();
#pragma unroll 4
    for (int k = 0; k < 16; ++k) {
      float4 wv[4];
      int s = (k ^ lane_o) & 15;
#pragma unroll
      for (int j = 0; j < 4; ++j) wv[j] = w4[(lane_o + 32 * j) * 16 + s];
#pragma unroll
      for (int r = 0; r < 8; ++r) {
        float4 av = A4[rowOff[r] + h * 16 + k];
#pragma unroll
        for (int j = 0; j < 4; ++j)
          acc[r][j] += av.x * wv[j].x + av.y * wv[j].y + av.z * wv[j].z + av.w * wv[j].w;
      }
    }
  }
#pragma unroll
  for (int r = 0; r < 8; ++r) {
    if (row0 + r < nrows) {
      float* orow = Out + (size_t)(row0 + r) * D_DIM;
#pragma unroll
      for (int j = 0; j < 4; ++j) orow[lane_o + 32 * j] = acc[r][j];
    }
  }
}

// out[n] (+)= sum of upd rows mapped to entity n (within [f0,f1)), optional relu.
__global__ __launch_bounds__(256) void final_add(const int* __restrict__ end_h,
                                                 const int* __restrict__ cnt_h,
                                                 const int* __restrict__ list,
                                                 const float* __restrict__ upd,
                                                 float* __restrict__ out, int f0,
                                                 int f1, int doRelu) {
  int n = blockIdx.x * 8 + (threadIdx.x >> 5);
  int lane = threadIdx.x & 31;
  if (n >= N_ENT) return;
  float4* o4 = (float4*)out + (size_t)n * 32 + lane;
  float4 v = *o4;
  int c = cnt_h[n];
  int s = end_h[n] - c;
  for (int k = 0; k < c; ++k) {
    int f = list[s + k];
    if (f < f0 || f >= f1) continue;
    const float4* u4 = (const float4*)upd + (size_t)(f - f0) * 32 + lane;
    float4 u = *u4;
    v.x += u.x; v.y += u.y; v.z += u.z; v.w += u.w;
  }
  if (doRelu) {
    v.x = fmaxf(v.x, 0.f); v.y = fmaxf(v.y, 0.f);
    v.z = fmaxf(v.z, 0.f); v.w = fmaxf(v.w, 0.f);
  }
  *o4 = v;
}

extern "C" void kernel_launch(void* const* d_in, const int* in_sizes, int n_in,
                              void* d_out, int out_size, void* d_ws, size_t ws_size,
                              hipStream_t stream) {
  const float* x = (const float*)d_in[0];
  const float* tail = (const float*)d_in[1];
  const float* W = (const float*)d_in[2];
  const float* relW = (const float*)d_in[3];
  const float* ew = (const float*)d_in[4];
  const int* erow = (const int*)d_in[5];
  const int* ecol = (const int*)d_in[6];
  const int* head = (const int*)d_in[7];
  float* out = (float*)d_out;

  // ws layout (16B-aligned chunks):
  char* p = (char*)d_ws;
  float* relT = (float*)p;   p += (size_t)R_REL * D_DIM * D_DIM * 4;
  int* cnt_e = (int*)p;      p += (size_t)R_REL * B_HEAD * 4;
  int* cnt_h = (int*)p;      p += (size_t)NH_PAD * 4;
  int* cur_e = (int*)p;      p += (size_t)R_REL * B_HEAD * 4;  // becomes end_e
  int* cur_h = (int*)p;      p += (size_t)NH_PAD * 4;          // becomes end_h
  int* list_h = (int*)p;     p += (size_t)R_REL * B_HEAD * 4;
  int2* sColW = (int2*)p;    p += (size_t)R_REL * E_EDGE * 8;
  float* agg = (float*)p;    // chunk * B * D floats (in-place: agg -> upd)
  size_t fixed = (size_t)(p - (char*)d_ws);
  size_t per_rel = (size_t)B_HEAD * D_DIM * 4;
  size_t avail = (ws_size > fixed) ? ws_size - fixed : 0;
  int chunk = (int)(avail / per_rel);
  if (chunk > R_REL) chunk = R_REL;
  if (chunk < 1) chunk = 1;

  zero_counts<<<dim3((R_REL * B_HEAD + NH_PAD) / 256), 256, 0, stream>>>(cnt_e);
  transpose_relW<<<dim3(16, R_REL), 256, 0, stream>>>(relW, relT);

  hist_edges<<<dim3(E_EDGE / 256, R_REL), 256, 0, stream>>>(erow, cnt_e);
  hist_heads<<<dim3(R_REL * B_HEAD / 256), 256, 0, stream>>>(head, cnt_h);
  scan_rel<<<dim3(R_REL), 1024, 0, stream>>>(cnt_e, cur_e);
  scan_heads<<<dim3(1), 1024, 0, stream>>>(cnt_h, cur_h);
  scatter_edges<<<dim3(E_EDGE / 256, R_REL), 256, 0, stream>>>(erow, ecol, ew, cur_e,
                                                               sColW);
  scatter_heads<<<dim3(R_REL * B_HEAD / 256), 256, 0, stream>>>(head, cur_h, list_h);

  gemm_k<false><<<dim3((N_ENT + 63) / 64), 256, 0, stream>>>(x, W, out, 0, N_ENT);

  for (int r0 = 0; r0 < R_REL; r0 += chunk) {
    int c = (R_REL - r0 < chunk) ? (R_REL - r0) : chunk;
    csr_agg<<<dim3(c * B_HEAD / 4), 256, 0, stream>>>(tail, cur_e, cnt_e, sColW, agg,
                                                      r0);
    gemm_k<true><<<dim3(B_HEAD / 64, c), 256, 0, stream>>>(agg, relT, agg, r0,
                                                           B_HEAD);
    final_add<<<dim3((N_ENT + 7) / 8), 256, 0, stream>>>(
        cur_h, cnt_h, list_h, agg, out, r0 * B_HEAD, (r0 + c) * B_HEAD,
        (r0 + c == R_REL) ? 1 : 0);
  }
}

// Round 5
// 577.678 us; speedup vs baseline: 2.1387x; 1.3629x over previous
//
#include <hip/hip_runtime.h>
#include <hip/hip_bf16.h>

#define D_DIM 128
#define N_ENT 100000
#define R_REL 8
#define E_EDGE 131072
#define B_HEAD 32768
#define NH_PAD 100352  // 1024*98 >= N_ENT

typedef __attribute__((ext_vector_type(8))) short short8v;
typedef __attribute__((ext_vector_type(16))) float f32x16;

union BF8 {
  short8v v;
  __hip_bfloat16 h[8];
};

// ---------- CSR build ----------
__global__ __launch_bounds__(256) void zero_counts(int* __restrict__ p) {
  p[blockIdx.x * 256 + threadIdx.x] = 0;  // exact grid
}

__global__ __launch_bounds__(256) void hist_edges(const int* __restrict__ erow,
                                                  int* __restrict__ cnt) {
  int r = blockIdx.y;
  int e = blockIdx.x * 256 + threadIdx.x;
  int row = erow[(size_t)r * E_EDGE + e];
  atomicAdd(cnt + r * B_HEAD + row, 1);
}

__global__ __launch_bounds__(256) void hist_heads(const int* __restrict__ head,
                                                  int* __restrict__ cnt) {
  int i = blockIdx.x * 256 + threadIdx.x;  // < R*B
  atomicAdd(cnt + head[i], 1);
}

__global__ __launch_bounds__(1024) void scan_rel(const int* __restrict__ cnt,
                                                 int* __restrict__ cur) {
  int r = blockIdx.x, t = threadIdx.x;
  const int* c = cnt + (size_t)r * B_HEAD;
  int* q = cur + (size_t)r * B_HEAD;
  int base = t * 32;
  int s = 0;
#pragma unroll
  for (int k = 0; k < 32; ++k) s += c[base + k];
  __shared__ int ps[1024];
  ps[t] = s;
  __syncthreads();
  for (int off = 1; off < 1024; off <<= 1) {
    int v = (t >= off) ? ps[t - off] : 0;
    __syncthreads();
    ps[t] += v;
    __syncthreads();
  }
  int g = r * E_EDGE + ps[t] - s;
  for (int k = 0; k < 32; ++k) {
    q[base + k] = g;
    g += c[base + k];
  }
}

__global__ __launch_bounds__(1024) void scan_heads(const int* __restrict__ cnt,
                                                   int* __restrict__ cur) {
  int t = threadIdx.x;
  int base = t * 98;
  int s = 0;
  for (int k = 0; k < 98; ++k) {
    int i = base + k;
    if (i < N_ENT) s += cnt[i];
  }
  __shared__ int ps[1024];
  ps[t] = s;
  __syncthreads();
  for (int off = 1; off < 1024; off <<= 1) {
    int v = (t >= off) ? ps[t - off] : 0;
    __syncthreads();
    ps[t] += v;
    __syncthreads();
  }
  int g = ps[t] - s;
  for (int k = 0; k < 98; ++k) {
    int i = base + k;
    if (i < N_ENT) {
      cur[i] = g;
      g += cnt[i];
    }
  }
}

__global__ __launch_bounds__(256) void scatter_edges(const int* __restrict__ erow,
                                                     const int* __restrict__ ecol,
                                                     const float* __restrict__ ew,
                                                     int* __restrict__ cur,
                                                     int2* __restrict__ sColW) {
  int r = blockIdx.y;
  int e = blockIdx.x * 256 + threadIdx.x;
  size_t idx = (size_t)r * E_EDGE + e;
  int row = erow[idx];
  int pos = atomicAdd(cur + r * B_HEAD + row, 1);
  sColW[pos] = make_int2(ecol[idx], __float_as_int(ew[idx]));
}

__global__ __launch_bounds__(256) void scatter_heads(const int* __restrict__ head,
                                                     int* __restrict__ cur,
                                                     int* __restrict__ list) {
  int i = blockIdx.x * 256 + threadIdx.x;  // flat (r,row) id
  int pos = atomicAdd(cur + head[i], 1);
  list[pos] = i;
}

// ---------- aggregation: one wave per (r,row); agg[row_local][:] = sum w*tail[col][:]
__global__ __launch_bounds__(256) void csr_agg(const float* __restrict__ tail,
                                               const int* __restrict__ end_e,
                                               const int* __restrict__ cnt_e,
                                               const int2* __restrict__ sColW,
                                               float* __restrict__ agg, int r0) {
  int wid = (blockIdx.x << 2) + (threadIdx.x >> 6);  // chunk-local row id
  int lane = threadIdx.x & 63;
  int f = r0 * B_HEAD + wid;  // global (r,row) id
  int cn = cnt_e[f];
  int s = end_e[f] - cn;
  const float2* tail2 = (const float2*)tail;
  float2 a0 = {0.f, 0.f}, a1 = {0.f, 0.f};
  int k = 0;
  for (; k + 2 <= cn; k += 2) {
    int2 e0 = sColW[s + k];
    int2 e1 = sColW[s + k + 1];
    float2 t0 = tail2[(size_t)e0.x * 64 + lane];
    float2 t1 = tail2[(size_t)e1.x * 64 + lane];
    float w0 = __int_as_float(e0.y), w1 = __int_as_float(e1.y);
    a0.x += w0 * t0.x; a0.y += w0 * t0.y;
    a1.x += w1 * t1.x; a1.y += w1 * t1.y;
  }
  if (k < cn) {
    int2 e0 = sColW[s + k];
    float2 t0 = tail2[(size_t)e0.x * 64 + lane];
    float w0 = __int_as_float(e0.y);
    a0.x += w0 * t0.x; a0.y += w0 * t0.y;
  }
  a0.x += a1.x; a0.y += a1.y;
  ((float2*)agg)[(size_t)wid * 64 + lane] = a0;
}

// ---------- W prep: build hi/lo bf16 slot-major images ----------
// Math: out[n][o] = sum_i A[n][i] * M[i][o].
//   mat 0   : M[i][o] = W[o][i]          (W given [o][i])
//   mat 1+r : M[i][o] = relW[r][i][o]    (given [i][o])
// Slot image: S[mat][ks*128+o] = bf16 of M[ks*8+j][o], j=0..7 packed in short8.
__global__ __launch_bounds__(256) void prep_W(const float* __restrict__ W,
                                              const float* __restrict__ relW,
                                              short8v* __restrict__ WhS,
                                              short8v* __restrict__ WlS) {
  int mat = blockIdx.y;
  int idx = blockIdx.x * 256 + threadIdx.x;  // 0..2047
  int o = idx & 127, ks = idx >> 7;
  float v[8];
  if (mat == 0) {
    const float* src = W + o * D_DIM + ks * 8;
#pragma unroll
    for (int j = 0; j < 8; ++j) v[j] = src[j];
  } else {
    const float* src = relW + (size_t)(mat - 1) * D_DIM * D_DIM + (ks * 8) * D_DIM + o;
#pragma unroll
    for (int j = 0; j < 8; ++j) v[j] = src[j * D_DIM];
  }
  BF8 h, l;
#pragma unroll
  for (int j = 0; j < 8; ++j) {
    __hip_bfloat16 hb = __float2bfloat16(v[j]);
    h.h[j] = hb;
    l.h[j] = __float2bfloat16(v[j] - __bfloat162float(hb));
  }
  WhS[(size_t)mat * 2048 + idx] = h.v;
  WlS[(size_t)mat * 2048 + idx] = l.v;
}

// ---------- MFMA GEMM: out[n][o] = sum_i A[n][i]*M[i][o], split-bf16 (4 products).
// 128-row x 128-col block tile, 4 waves (wave w owns rows w*32..+32, all 128 cols).
// A: f32 from global, converted in-register. B: LDS slot-major [ks][o], linear reads.
template <bool REL>
__global__ __launch_bounds__(256) void gemm_mfma(const float* __restrict__ Abase,
                                                 const short8v* __restrict__ WhS,
                                                 const short8v* __restrict__ WlS,
                                                 float* __restrict__ Obase, int r0,
                                                 int nrows) {
  __shared__ short8v wlds[2][8][128];  // 32 KB: [hi/lo][ks(half)][o]
  int tid = threadIdx.x;
  const float* A;
  float* Out;
  int mat;
  if (REL) {
    A = Abase + (size_t)blockIdx.y * B_HEAD * D_DIM;
    Out = Obase + (size_t)blockIdx.y * B_HEAD * D_DIM;
    mat = 1 + r0 + blockIdx.y;
  } else {
    A = Abase;
    Out = Obase;
    mat = 0;
  }
  const short8v* Hsrc = WhS + (size_t)mat * 2048;
  const short8v* Lsrc = WlS + (size_t)mat * 2048;
  int w = tid >> 6, lane = tid & 63, lrow = lane & 31, lsel = lane >> 5;
  int arow = blockIdx.x * 128 + w * 32 + lrow;
  int arowc = (arow < nrows) ? arow : (nrows - 1);
  const float4* Arow = (const float4*)(A + (size_t)arowc * D_DIM);  // 32 float4

  f32x16 acc[4] = {};
  for (int half = 0; half < 2; ++half) {
    if (half) __syncthreads();
#pragma unroll
    for (int it = 0; it < 4; ++it) {
      int e = it * 256 + tid;  // 0..1023
      wlds[0][e >> 7][e & 127] = Hsrc[half * 1024 + e];
      wlds[1][e >> 7][e & 127] = Lsrc[half * 1024 + e];
    }
    __syncthreads();
#pragma unroll
    for (int kk = 0; kk < 4; ++kk) {
      int k0 = half * 64 + kk * 16;  // element-k base of this MFMA step
      float4 a0 = Arow[(k0 >> 2) + lsel * 2];
      float4 a1 = Arow[(k0 >> 2) + lsel * 2 + 1];
      float av[8] = {a0.x, a0.y, a0.z, a0.w, a1.x, a1.y, a1.z, a1.w};
      BF8 ah, al;
#pragma unroll
      for (int j = 0; j < 8; ++j) {
        __hip_bfloat16 hb = __float2bfloat16(av[j]);
        ah.h[j] = hb;
        al.h[j] = __float2bfloat16(av[j] - __bfloat162float(hb));
      }
      int ks = kk * 2 + lsel;
#pragma unroll
      for (int n = 0; n < 4; ++n) {
        short8v bh = wlds[0][ks][n * 32 + lrow];
        short8v bl = wlds[1][ks][n * 32 + lrow];
        acc[n] = __builtin_amdgcn_mfma_f32_32x32x16_bf16(ah.v, bh, acc[n], 0, 0, 0);
        acc[n] = __builtin_amdgcn_mfma_f32_32x32x16_bf16(ah.v, bl, acc[n], 0, 0, 0);
        acc[n] = __builtin_amdgcn_mfma_f32_32x32x16_bf16(al.v, bh, acc[n], 0, 0, 0);
        acc[n] = __builtin_amdgcn_mfma_f32_32x32x16_bf16(al.v, bl, acc[n], 0, 0, 0);
      }
    }
  }
  // C/D layout (m74/m101): col = lane&31, row = (reg&3) + 8*(reg>>2) + 4*(lane>>5)
  int wrow0 = blockIdx.x * 128 + w * 32;
#pragma unroll
  for (int reg = 0; reg < 16; ++reg) {
    int srow = wrow0 + (reg & 3) + 8 * (reg >> 2) + 4 * lsel;
    if (srow < nrows) {
      float* orow = Out + (size_t)srow * D_DIM;
#pragma unroll
      for (int n = 0; n < 4; ++n) orow[n * 32 + lrow] = acc[n][reg];
    }
  }
}

// out[n] (+)= sum of upd rows mapped to entity n (within [f0,f1)), optional relu.
__global__ __launch_bounds__(256) void final_add(const int* __restrict__ end_h,
                                                 const int* __restrict__ cnt_h,
                                                 const int* __restrict__ list,
                                                 const float* __restrict__ upd,
                                                 float* __restrict__ out, int f0,
                                                 int f1, int doRelu) {
  int n = blockIdx.x * 8 + (threadIdx.x >> 5);
  int lane = threadIdx.x & 31;
  if (n >= N_ENT) return;
  float4* o4 = (float4*)out + (size_t)n * 32 + lane;
  float4 v = *o4;
  int c = cnt_h[n];
  int s = end_h[n] - c;
  for (int k = 0; k < c; ++k) {
    int f = list[s + k];
    if (f < f0 || f >= f1) continue;
    const float4* u4 = (const float4*)upd + (size_t)(f - f0) * 32 + lane;
    float4 u = *u4;
    v.x += u.x; v.y += u.y; v.z += u.z; v.w += u.w;
  }
  if (doRelu) {
    v.x = fmaxf(v.x, 0.f); v.y = fmaxf(v.y, 0.f);
    v.z = fmaxf(v.z, 0.f); v.w = fmaxf(v.w, 0.f);
  }
  *o4 = v;
}

extern "C" void kernel_launch(void* const* d_in, const int* in_sizes, int n_in,
                              void* d_out, int out_size, void* d_ws, size_t ws_size,
                              hipStream_t stream) {
  const float* x = (const float*)d_in[0];
  const float* tail = (const float*)d_in[1];
  const float* W = (const float*)d_in[2];
  const float* relW = (const float*)d_in[3];
  const float* ew = (const float*)d_in[4];
  const int* erow = (const int*)d_in[5];
  const int* ecol = (const int*)d_in[6];
  const int* head = (const int*)d_in[7];
  float* out = (float*)d_out;

  // ws layout (16B-aligned chunks):
  char* p = (char*)d_ws;
  short8v* WhS = (short8v*)p; p += (size_t)(R_REL + 1) * 2048 * 16;
  short8v* WlS = (short8v*)p; p += (size_t)(R_REL + 1) * 2048 * 16;
  int* cnt_e = (int*)p;       p += (size_t)R_REL * B_HEAD * 4;
  int* cnt_h = (int*)p;       p += (size_t)NH_PAD * 4;
  int* cur_e = (int*)p;       p += (size_t)R_REL * B_HEAD * 4;  // becomes end_e
  int* cur_h = (int*)p;       p += (size_t)NH_PAD * 4;          // becomes end_h
  int* list_h = (int*)p;      p += (size_t)R_REL * B_HEAD * 4;
  int2* sColW = (int2*)p;     p += (size_t)R_REL * E_EDGE * 8;
  float* agg = (float*)p;     // chunk * B * D floats (in-place: agg -> upd)
  size_t fixed = (size_t)(p - (char*)d_ws);
  size_t per_rel = (size_t)B_HEAD * D_DIM * 4;
  size_t avail = (ws_size > fixed) ? ws_size - fixed : 0;
  int chunk = (int)(avail / per_rel);
  if (chunk > R_REL) chunk = R_REL;
  if (chunk < 1) chunk = 1;

  zero_counts<<<dim3((R_REL * B_HEAD + NH_PAD) / 256), 256, 0, stream>>>(cnt_e);
  prep_W<<<dim3(8, R_REL + 1), 256, 0, stream>>>(W, relW, WhS, WlS);

  hist_edges<<<dim3(E_EDGE / 256, R_REL), 256, 0, stream>>>(erow, cnt_e);
  hist_heads<<<dim3(R_REL * B_HEAD / 256), 256, 0, stream>>>(head, cnt_h);
  scan_rel<<<dim3(R_REL), 1024, 0, stream>>>(cnt_e, cur_e);
  scan_heads<<<dim3(1), 1024, 0, stream>>>(cnt_h, cur_h);
  scatter_edges<<<dim3(E_EDGE / 256, R_REL), 256, 0, stream>>>(erow, ecol, ew, cur_e,
                                                               sColW);
  scatter_heads<<<dim3(R_REL * B_HEAD / 256), 256, 0, stream>>>(head, cur_h, list_h);

  gemm_mfma<false><<<dim3((N_ENT + 127) / 128), 256, 0, stream>>>(x, WhS, WlS, out, 0,
                                                                  N_ENT);

  for (int r0 = 0; r0 < R_REL; r0 += chunk) {
    int c = (R_REL - r0 < chunk) ? (R_REL - r0) : chunk;
    csr_agg<<<dim3(c * B_HEAD / 4), 256, 0, stream>>>(tail, cur_e, cnt_e, sColW, agg,
                                                      r0);
    gemm_mfma<true><<<dim3(B_HEAD / 128, c), 256, 0, stream>>>(agg, WhS, WlS, agg, r0,
                                                               B_HEAD);
    final_add<<<dim3((N_ENT + 7) / 8), 256, 0, stream>>>(
        cur_h, cnt_h, list_h, agg, out, r0 * B_HEAD, (r0 + c) * B_HEAD,
        (r0 + c == R_REL) ? 1 : 0);
  }
}

// Round 6
// 369.323 us; speedup vs baseline: 3.3452x; 1.5642x over previous
//
#include <hip/hip_runtime.h>
#include <hip/hip_bf16.h>

#define D_DIM 128
#define N_ENT 100000
#define R_REL 8
#define E_EDGE 131072
#define B_HEAD 32768
#define NH_PAD 100352  // multiple of 256 >= N_ENT

typedef __attribute__((ext_vector_type(8))) short short8v;
typedef __attribute__((ext_vector_type(16))) float f32x16;

union BF8 {
  short8v v;
  __hip_bfloat16 h[8];
};

// ---------- init: cnt_e = 0, inv = -1 ----------
__global__ __launch_bounds__(256) void init_ws(int* __restrict__ cnt_e,
                                               int* __restrict__ inv) {
  int i = blockIdx.x * 256 + threadIdx.x;  // grid covers R*NH_PAD
  if (i < R_REL * B_HEAD) cnt_e[i] = 0;
  inv[i] = -1;
}

// ---------- CSR build (edges) ----------
__global__ __launch_bounds__(256) void hist_edges(const int* __restrict__ erow,
                                                  int* __restrict__ cnt) {
  int r = blockIdx.y;
  int e = blockIdx.x * 256 + threadIdx.x;
  int row = erow[(size_t)r * E_EDGE + e];
  atomicAdd(cnt + r * B_HEAD + row, 1);
}

// 3-phase exclusive scan over R*B = 262144 ints.
// Phase A: 256 blocks x 1024 elems (int4 per thread), local exclusive + block sum.
__global__ __launch_bounds__(256) void scan_blk(const int* __restrict__ cnt,
                                                int* __restrict__ cur,
                                                int* __restrict__ bsum) {
  int b = blockIdx.x, t = threadIdx.x;
  int4 v = ((const int4*)cnt)[b * 256 + t];
  int s = v.x + v.y + v.z + v.w;
  __shared__ int ps[256];
  ps[t] = s;
  __syncthreads();
  for (int off = 1; off < 256; off <<= 1) {
    int u = (t >= off) ? ps[t - off] : 0;
    __syncthreads();
    ps[t] += u;
    __syncthreads();
  }
  int base = ps[t] - s;
  int4 o;
  o.x = base;
  o.y = base + v.x;
  o.z = o.y + v.y;
  o.w = o.z + v.z;
  ((int4*)cur)[b * 256 + t] = o;
  if (t == 255) bsum[b] = ps[255];
}

// Phase B: exclusive scan of the 256 block sums.
__global__ __launch_bounds__(256) void scan_bsum(int* __restrict__ bsum) {
  int t = threadIdx.x;
  int s = bsum[t];
  __shared__ int ps[256];
  ps[t] = s;
  __syncthreads();
  for (int off = 1; off < 256; off <<= 1) {
    int u = (t >= off) ? ps[t - off] : 0;
    __syncthreads();
    ps[t] += u;
    __syncthreads();
  }
  bsum[t] = ps[t] - s;
}

// Phase C: add block offsets (i is int4 index; 256 int4 per scan block).
__global__ __launch_bounds__(256) void scan_add(int* __restrict__ cur,
                                                const int* __restrict__ bsum) {
  int i = blockIdx.x * 256 + threadIdx.x;
  int o = bsum[i >> 8];
  int4 v = ((int4*)cur)[i];
  v.x += o; v.y += o; v.z += o; v.w += o;
  ((int4*)cur)[i] = v;
}

__global__ __launch_bounds__(256) void scatter_edges(const int* __restrict__ erow,
                                                     const int* __restrict__ ecol,
                                                     const float* __restrict__ ew,
                                                     int* __restrict__ cur,
                                                     int2* __restrict__ sColW) {
  int r = blockIdx.y;
  int e = blockIdx.x * 256 + threadIdx.x;
  size_t idx = (size_t)r * E_EDGE + e;
  int row = erow[idx];
  int pos = atomicAdd(cur + r * B_HEAD + row, 1);
  sColW[pos] = make_int2(ecol[idx], __float_as_int(ew[idx]));
}

// inv[r][head[r][i]] = i  (head entries unique per relation -> race-free)
__global__ __launch_bounds__(256) void build_inv(const int* __restrict__ head,
                                                 int* __restrict__ inv) {
  int i = blockIdx.x * 256 + threadIdx.x;  // 0..R*B
  int r = i >> 15;                         // B = 32768
  inv[r * NH_PAD + head[i]] = i & (B_HEAD - 1);
}

// ---------- aggregation: one wave per (r,row); agg[row_local][:] = sum w*tail[col][:]
__global__ __launch_bounds__(256) void csr_agg(const float* __restrict__ tail,
                                               const int* __restrict__ end_e,
                                               const int* __restrict__ cnt_e,
                                               const int2* __restrict__ sColW,
                                               float* __restrict__ agg, int r0) {
  int wid = (blockIdx.x << 2) + (threadIdx.x >> 6);  // chunk-local row id
  int lane = threadIdx.x & 63;
  int f = r0 * B_HEAD + wid;  // global (r,row) id
  int cn = cnt_e[f];
  int s = end_e[f] - cn;
  const float2* tail2 = (const float2*)tail;
  float2 a0 = {0.f, 0.f}, a1 = {0.f, 0.f};
  int k = 0;
  for (; k + 2 <= cn; k += 2) {
    int2 e0 = sColW[s + k];
    int2 e1 = sColW[s + k + 1];
    float2 t0 = tail2[(size_t)e0.x * 64 + lane];
    float2 t1 = tail2[(size_t)e1.x * 64 + lane];
    float w0 = __int_as_float(e0.y), w1 = __int_as_float(e1.y);
    a0.x += w0 * t0.x; a0.y += w0 * t0.y;
    a1.x += w1 * t1.x; a1.y += w1 * t1.y;
  }
  if (k < cn) {
    int2 e0 = sColW[s + k];
    float2 t0 = tail2[(size_t)e0.x * 64 + lane];
    float w0 = __int_as_float(e0.y);
    a0.x += w0 * t0.x; a0.y += w0 * t0.y;
  }
  a0.x += a1.x; a0.y += a1.y;
  ((float2*)agg)[(size_t)wid * 64 + lane] = a0;
}

// ---------- W prep: hi/lo bf16 slot-major images ----------
// out[n][o] = sum_i A[n][i]*M[i][o]; mat0: M=W^T, mat1+r: M=relW[r].
__global__ __launch_bounds__(256) void prep_W(const float* __restrict__ W,
                                              const float* __restrict__ relW,
                                              short8v* __restrict__ WhS,
                                              short8v* __restrict__ WlS) {
  int mat = blockIdx.y;
  int idx = blockIdx.x * 256 + threadIdx.x;  // 0..2047
  int o = idx & 127, ks = idx >> 7;
  float v[8];
  if (mat == 0) {
    const float* src = W + o * D_DIM + ks * 8;
#pragma unroll
    for (int j = 0; j < 8; ++j) v[j] = src[j];
  } else {
    const float* src = relW + (size_t)(mat - 1) * D_DIM * D_DIM + (ks * 8) * D_DIM + o;
#pragma unroll
    for (int j = 0; j < 8; ++j) v[j] = src[j * D_DIM];
  }
  BF8 h, l;
#pragma unroll
  for (int j = 0; j < 8; ++j) {
    __hip_bfloat16 hb = __float2bfloat16(v[j]);
    h.h[j] = hb;
    l.h[j] = __float2bfloat16(v[j] - __bfloat162float(hb));
  }
  WhS[(size_t)mat * 2048 + idx] = h.v;
  WlS[(size_t)mat * 2048 + idx] = l.v;
}

// ---------- MFMA GEMM (split-bf16, 4 products), 128x128 tile, 4 waves ----------
template <bool REL>
__global__ __launch_bounds__(256) void gemm_mfma(const float* __restrict__ Abase,
                                                 const short8v* __restrict__ WhS,
                                                 const short8v* __restrict__ WlS,
                                                 float* __restrict__ Obase, int r0,
                                                 int nrows) {
  __shared__ short8v wlds[2][8][128];  // 32 KB
  int tid = threadIdx.x;
  const float* A;
  float* Out;
  int mat;
  if (REL) {
    A = Abase + (size_t)blockIdx.y * B_HEAD * D_DIM;
    Out = Obase + (size_t)blockIdx.y * B_HEAD * D_DIM;
    mat = 1 + r0 + blockIdx.y;
  } else {
    A = Abase;
    Out = Obase;
    mat = 0;
  }
  const short8v* Hsrc = WhS + (size_t)mat * 2048;
  const short8v* Lsrc = WlS + (size_t)mat * 2048;
  int w = tid >> 6, lane = tid & 63, lrow = lane & 31, lsel = lane >> 5;
  int arow = blockIdx.x * 128 + w * 32 + lrow;
  int arowc = (arow < nrows) ? arow : (nrows - 1);
  const float4* Arow = (const float4*)(A + (size_t)arowc * D_DIM);

  f32x16 acc[4] = {};
  for (int half = 0; half < 2; ++half) {
    if (half) __syncthreads();
#pragma unroll
    for (int it = 0; it < 4; ++it) {
      int e = it * 256 + tid;
      wlds[0][e >> 7][e & 127] = Hsrc[half * 1024 + e];
      wlds[1][e >> 7][e & 127] = Lsrc[half * 1024 + e];
    }
    __syncthreads();
#pragma unroll
    for (int kk = 0; kk < 4; ++kk) {
      int k0 = half * 64 + kk * 16;
      float4 a0 = Arow[(k0 >> 2) + lsel * 2];
      float4 a1 = Arow[(k0 >> 2) + lsel * 2 + 1];
      float av[8] = {a0.x, a0.y, a0.z, a0.w, a1.x, a1.y, a1.z, a1.w};
      BF8 ah, al;
#pragma unroll
      for (int j = 0; j < 8; ++j) {
        __hip_bfloat16 hb = __float2bfloat16(av[j]);
        ah.h[j] = hb;
        al.h[j] = __float2bfloat16(av[j] - __bfloat162float(hb));
      }
      int ks = kk * 2 + lsel;
#pragma unroll
      for (int n = 0; n < 4; ++n) {
        short8v bh = wlds[0][ks][n * 32 + lrow];
        short8v bl = wlds[1][ks][n * 32 + lrow];
        acc[n] = __builtin_amdgcn_mfma_f32_32x32x16_bf16(ah.v, bh, acc[n], 0, 0, 0);
        acc[n] = __builtin_amdgcn_mfma_f32_32x32x16_bf16(ah.v, bl, acc[n], 0, 0, 0);
        acc[n] = __builtin_amdgcn_mfma_f32_32x32x16_bf16(al.v, bh, acc[n], 0, 0, 0);
        acc[n] = __builtin_amdgcn_mfma_f32_32x32x16_bf16(al.v, bl, acc[n], 0, 0, 0);
      }
    }
  }
  int wrow0 = blockIdx.x * 128 + w * 32;
#pragma unroll
  for (int reg = 0; reg < 16; ++reg) {
    int srow = wrow0 + (reg & 3) + 8 * (reg >> 2) + 4 * lsel;
    if (srow < nrows) {
      float* orow = Out + (size_t)srow * D_DIM;
#pragma unroll
      for (int n = 0; n < 4; ++n) orow[n * 32 + lrow] = acc[n][reg];
    }
  }
}

// out[n] += upd rows of relations [r0, r0+c) whose head set contains n; optional relu.
__global__ __launch_bounds__(256) void final_add(const int* __restrict__ inv,
                                                 const float* __restrict__ upd,
                                                 float* __restrict__ out, int r0,
                                                 int c, int doRelu) {
  int n = blockIdx.x * 8 + (threadIdx.x >> 5);
  int lane = threadIdx.x & 31;
  if (n >= N_ENT) return;
  float4* o4 = (float4*)out + (size_t)n * 32 + lane;
  float4 v = *o4;
  for (int k = 0; k < c; ++k) {
    int row = inv[(r0 + k) * NH_PAD + n];
    if (row >= 0) {
      const float4* u4 = (const float4*)upd + ((size_t)k * B_HEAD + row) * 32 + lane;
      float4 u = *u4;
      v.x += u.x; v.y += u.y; v.z += u.z; v.w += u.w;
    }
  }
  if (doRelu) {
    v.x = fmaxf(v.x, 0.f); v.y = fmaxf(v.y, 0.f);
    v.z = fmaxf(v.z, 0.f); v.w = fmaxf(v.w, 0.f);
  }
  *o4 = v;
}

extern "C" void kernel_launch(void* const* d_in, const int* in_sizes, int n_in,
                              void* d_out, int out_size, void* d_ws, size_t ws_size,
                              hipStream_t stream) {
  const float* x = (const float*)d_in[0];
  const float* tail = (const float*)d_in[1];
  const float* W = (const float*)d_in[2];
  const float* relW = (const float*)d_in[3];
  const float* ew = (const float*)d_in[4];
  const int* erow = (const int*)d_in[5];
  const int* ecol = (const int*)d_in[6];
  const int* head = (const int*)d_in[7];
  float* out = (float*)d_out;

  // ws layout (16B-aligned chunks):
  char* p = (char*)d_ws;
  short8v* WhS = (short8v*)p; p += (size_t)(R_REL + 1) * 2048 * 16;
  short8v* WlS = (short8v*)p; p += (size_t)(R_REL + 1) * 2048 * 16;
  int* cnt_e = (int*)p;       p += (size_t)R_REL * B_HEAD * 4;
  int* cur_e = (int*)p;       p += (size_t)R_REL * B_HEAD * 4;  // becomes end_e
  int* inv = (int*)p;         p += (size_t)R_REL * NH_PAD * 4;
  int* bsum = (int*)p;        p += 256 * 4;
  int2* sColW = (int2*)p;     p += (size_t)R_REL * E_EDGE * 8;
  float* agg = (float*)p;     // chunk * B * D floats
  size_t fixed = (size_t)(p - (char*)d_ws);
  size_t per_rel = (size_t)B_HEAD * D_DIM * 4;
  size_t avail = (ws_size > fixed) ? ws_size - fixed : 0;
  int chunk = (int)(avail / per_rel);
  if (chunk > R_REL) chunk = R_REL;
  if (chunk < 1) chunk = 1;

  init_ws<<<dim3(R_REL * NH_PAD / 256), 256, 0, stream>>>(cnt_e, inv);
  prep_W<<<dim3(8, R_REL + 1), 256, 0, stream>>>(W, relW, WhS, WlS);

  hist_edges<<<dim3(E_EDGE / 256, R_REL), 256, 0, stream>>>(erow, cnt_e);
  scan_blk<<<dim3(256), 256, 0, stream>>>(cnt_e, cur_e, bsum);
  scan_bsum<<<dim3(1), 256, 0, stream>>>(bsum);
  scan_add<<<dim3(256), 256, 0, stream>>>(cur_e, bsum);
  scatter_edges<<<dim3(E_EDGE / 256, R_REL), 256, 0, stream>>>(erow, ecol, ew, cur_e,
                                                               sColW);
  build_inv<<<dim3(R_REL * B_HEAD / 256), 256, 0, stream>>>(head, inv);

  gemm_mfma<false><<<dim3((N_ENT + 127) / 128), 256, 0, stream>>>(x, WhS, WlS, out, 0,
                                                                  N_ENT);

  for (int r0 = 0; r0 < R_REL; r0 += chunk) {
    int c = (R_REL - r0 < chunk) ? (R_REL - r0) : chunk;
    csr_agg<<<dim3(c * B_HEAD / 4), 256, 0, stream>>>(tail, cur_e, cnt_e, sColW, agg,
                                                      r0);
    gemm_mfma<true><<<dim3(B_HEAD / 128, c), 256, 0, stream>>>(agg, WhS, WlS, agg, r0,
                                                               B_HEAD);
    final_add<<<dim3((N_ENT + 7) / 8), 256, 0, stream>>>(inv, agg, out, r0, c,
                                                         (r0 + c == R_REL) ? 1 : 0);
  }
}